// Round 1
// baseline (2735.161 us; speedup 1.0000x reference)
//
#include <hip/hip_runtime.h>
#include <math.h>

#define BB 8
#define NN 768
#define TT 769
#define DD 256
#define HH 8
#define DKK 32
#define FF 128
#define LL 6
#define SCALE 0.17677669529663687f   // 1/sqrt(32)

// ---------------- degree: deg[b,i] = sum_j adj[b,i,j] ----------------
__global__ __launch_bounds__(256) void deg_kernel(const int* __restrict__ adj,
                                                  float* __restrict__ deg) {
    int row  = blockIdx.x * 4 + (threadIdx.x >> 6);   // 0..6143 (b*NN+i)
    int lane = threadIdx.x & 63;
    const int* p = adj + (size_t)row * NN;
    int s = 0;
#pragma unroll
    for (int i = 0; i < NN / 64; ++i) s += p[lane + 64 * i];
#pragma unroll
    for (int off = 32; off > 0; off >>= 1) s += __shfl_xor(s, off);
    if (lane == 0) deg[row] = (float)s;
}

__global__ __launch_bounds__(256) void degmax_kernel(const float* __restrict__ deg,
                                                     float* __restrict__ dmax) {
    __shared__ float red[256];
    int b = blockIdx.x, t = threadIdx.x;
    float m = 0.f;
    for (int i = t; i < NN; i += 256) m = fmaxf(m, deg[b * NN + i]);
    red[t] = m;
    __syncthreads();
    for (int s = 128; s > 0; s >>= 1) {
        if (t < s) red[t] = fmaxf(red[t], red[t + s]);
        __syncthreads();
    }
    if (t == 0) dmax[b] = red[0];
}

// ---------------- attention bias (B,T,T) ----------------
__global__ __launch_bounds__(256) void bias_kernel(
    const float* __restrict__ dist, const float* __restrict__ eoh,
    const int* __restrict__ adj, const float* __restrict__ deg,
    const float* __restrict__ dmax, const float* __restrict__ etw,
    const float* __restrict__ noedge, const float* __restrict__ degsc,
    const float* __restrict__ gamma, const float* __restrict__ v2n,
    const float* __restrict__ n2v, const float* __restrict__ vself,
    float* __restrict__ bias)
{
    long long idx = (long long)blockIdx.x * 256 + threadIdx.x;
    const long long total = (long long)BB * TT * TT;
    if (idx >= total) return;
    int b  = (int)(idx / ((long long)TT * TT));
    int r  = (int)(idx % ((long long)TT * TT));
    int qi = r / TT, kj = r % TT;
    float out;
    if (qi == 0 && kj == 0) out = vself[0];
    else if (qi == 0)       out = v2n[0];
    else if (kj == 0)       out = n2v[0];
    else {
        int i = qi - 1, j = kj - 1;
        size_t e = ((size_t)b * NN + i) * NN + j;
        float4 oh = *(const float4*)(eoh + 4 * e);
        float val = oh.x * etw[0] + oh.y * etw[1] + oh.z * etw[2] + oh.w * etw[3]
                    - gamma[0] * dist[e];
        if (adj[e] == 0) val += noedge[0];
        val += degsc[0] * (deg[b * NN + i] + deg[b * NN + j]) / (dmax[b] + 1e-6f);
        out = val;
    }
    bias[idx] = out;
}

// ---------------- node projection + cls row -> x (lives in d_out) ----------------
__global__ __launch_bounds__(256) void nodeproj_kernel(
    const float* __restrict__ nf, const float* __restrict__ w,
    const float* __restrict__ bsv, const float* __restrict__ cls,
    float* __restrict__ x)
{
    int row = blockIdx.x;   // 0..6151 = b*TT + tr
    int t = threadIdx.x;
    int b = row / TT, tr = row % TT;
    if (tr == 0) { x[(size_t)row * DD + t] = cls[t]; return; }   // uniform per block
    __shared__ float sf[FF];
    int i = tr - 1;
    if (t < FF) sf[t] = nf[((size_t)b * NN + i) * FF + t];
    __syncthreads();
    float acc = bsv[t];
#pragma unroll 8
    for (int k = 0; k < FF; ++k) acc = fmaf(sf[k], w[k * DD + t], acc);
    x[(size_t)row * DD + t] = acc;
}

// ---------------- layernorm (one row per block, D=256) ----------------
__global__ __launch_bounds__(256) void ln_kernel(
    const float* __restrict__ x, const float* __restrict__ g,
    const float* __restrict__ bsv, float* __restrict__ out)
{
    __shared__ float red[256];
    int row = blockIdx.x, t = threadIdx.x;
    float v = x[(size_t)row * DD + t];
    red[t] = v;
    __syncthreads();
    for (int s = 128; s > 0; s >>= 1) { if (t < s) red[t] += red[t + s]; __syncthreads(); }
    float mean = red[0] * (1.f / DD);
    __syncthreads();
    float d = v - mean;
    red[t] = d * d;
    __syncthreads();
    for (int s = 128; s > 0; s >>= 1) { if (t < s) red[t] += red[t + s]; __syncthreads(); }
    float var = red[0] * (1.f / DD);
    out[(size_t)row * DD + t] = d * rsqrtf(var + 1e-5f) * g[t] + bsv[t];
}

// ---------------- generic f32 GEMM: C = act(A(Mx256) @ W(256x256) + bias) [+ resid] ----------------
__device__ inline float gelu_f(float x) {
    return 0.5f * x * (1.f + erff(x * 0.70710678118654752f));
}

__global__ __launch_bounds__(256) void gemm256_kernel(
    const float* __restrict__ A, const float* __restrict__ W,
    const float* __restrict__ bsv, const float* __restrict__ resid,
    float* __restrict__ C, int M, int act)
{
    __shared__ float As[16][64];   // [k][m]
    __shared__ float Ws[16][64];   // [k][n]
    int t  = threadIdx.x;
    int tx = t & 15, ty = t >> 4;
    int m0 = blockIdx.x * 64, n0 = blockIdx.y * 64;
    int lm = t >> 2, lk = (t & 3) * 4;
    int wr = t >> 4, wc = (t & 15) * 4;
    float acc[4][4] = {};
    for (int k0 = 0; k0 < DD; k0 += 16) {
        float4 av = make_float4(0.f, 0.f, 0.f, 0.f);
        if (m0 + lm < M) av = *(const float4*)(A + (size_t)(m0 + lm) * DD + k0 + lk);
        As[lk + 0][lm] = av.x; As[lk + 1][lm] = av.y;
        As[lk + 2][lm] = av.z; As[lk + 3][lm] = av.w;
        *(float4*)&Ws[wr][wc] = *(const float4*)(W + (size_t)(k0 + wr) * DD + n0 + wc);
        __syncthreads();
#pragma unroll
        for (int kk = 0; kk < 16; ++kk) {
            float4 a4 = *(const float4*)&As[kk][ty * 4];
            float4 w4 = *(const float4*)&Ws[kk][tx * 4];
            float ar[4] = {a4.x, a4.y, a4.z, a4.w};
            float wr4[4] = {w4.x, w4.y, w4.z, w4.w};
#pragma unroll
            for (int r = 0; r < 4; ++r)
#pragma unroll
                for (int c = 0; c < 4; ++c)
                    acc[r][c] = fmaf(ar[r], wr4[c], acc[r][c]);
        }
        __syncthreads();
    }
#pragma unroll
    for (int r = 0; r < 4; ++r) {
        int row = m0 + ty * 4 + r;
        if (row >= M) continue;
#pragma unroll
        for (int c = 0; c < 4; ++c) {
            int col = n0 + tx * 4 + c;
            float v = acc[r][c] + bsv[col];
            if (act) v = gelu_f(v);
            if (resid) v += resid[(size_t)row * DD + col];
            C[(size_t)row * DD + col] = v;
        }
    }
}

// ---------------- fused attention: 8 query rows per block, one (b,h) ----------------
#define QT 8
#define JTILE 64
#define SP 832   // 13*64 score pitch

__global__ __launch_bounds__(256) void attn_kernel(
    const float* __restrict__ q, const float* __restrict__ k,
    const float* __restrict__ v, const float* __restrict__ bias,
    float* __restrict__ o)
{
    __shared__ float Ks[JTILE][DKK + 1];   // reused for V tiles
    __shared__ float sc[QT][SP];
    __shared__ float qs[QT][DKK];
    int t = threadIdx.x;
    int qt0 = blockIdx.x * QT;
    int h = blockIdx.y, b = blockIdx.z;
    int qi = t >> 5, lane = t & 31;

    int row = qt0 + qi;
    int valid_q = row < TT;
    qs[qi][lane] = valid_q ? q[((size_t)(b * TT + row)) * DD + h * DKK + lane] : 0.f;
    __syncthreads();
    float qr[DKK];
#pragma unroll
    for (int d = 0; d < DKK; ++d) qr[d] = qs[qi][d];
    const float* brow = bias + ((size_t)b * TT + (valid_q ? row : 0)) * TT;

    // ---- scores ----
    for (int jt = 0; jt < 13; ++jt) {
        int j0 = jt * JTILE;
        int jl = t >> 2, db = (t & 3) * 8;
        int jg = j0 + jl;
        if (jg < TT) {
            const float* kp = k + ((size_t)(b * TT + jg)) * DD + h * DKK + db;
#pragma unroll
            for (int i = 0; i < 8; ++i) Ks[jl][db + i] = kp[i];
        } else {
#pragma unroll
            for (int i = 0; i < 8; ++i) Ks[jl][db + i] = 0.f;
        }
        __syncthreads();
#pragma unroll
        for (int jj = 0; jj < 2; ++jj) {
            int jjl = lane + jj * 32;
            int jjg = j0 + jjl;
            float acc = 0.f;
#pragma unroll
            for (int d = 0; d < DKK; ++d) acc = fmaf(qr[d], Ks[jjl][d], acc);
            sc[qi][j0 + jjl] = (valid_q && jjg < TT) ? acc * SCALE + brow[jjg] : -1e30f;
        }
        __syncthreads();
    }

    // ---- softmax over 32-lane group ----
    float m = -1e30f;
    for (int j = lane; j < TT; j += 32) m = fmaxf(m, sc[qi][j]);
#pragma unroll
    for (int off = 16; off > 0; off >>= 1) m = fmaxf(m, __shfl_xor(m, off, 32));
    float sum = 0.f;
    for (int j = lane; j < TT; j += 32) {
        float e = __expf(sc[qi][j] - m);
        sc[qi][j] = e;
        sum += e;
    }
#pragma unroll
    for (int off = 16; off > 0; off >>= 1) sum += __shfl_xor(sum, off, 32);
    float rs = 1.f / sum;
    __syncthreads();

    // ---- P @ V ----
    float acc = 0.f;
    for (int jt = 0; jt < 13; ++jt) {
        int j0 = jt * JTILE;
        int jl = t >> 2, db = (t & 3) * 8;
        int jg = j0 + jl;
        if (jg < TT) {
            const float* vp = v + ((size_t)(b * TT + jg)) * DD + h * DKK + db;
#pragma unroll
            for (int i = 0; i < 8; ++i) Ks[jl][db + i] = vp[i];
        } else {
#pragma unroll
            for (int i = 0; i < 8; ++i) Ks[jl][db + i] = 0.f;
        }
        __syncthreads();
#pragma unroll 8
        for (int j2 = 0; j2 < JTILE; ++j2)
            acc = fmaf(sc[qi][j0 + j2], Ks[j2][lane], acc);
        __syncthreads();
    }
    if (valid_q) o[((size_t)(b * TT + row)) * DD + h * DKK + lane] = acc * rs;
}

// ---------------- host ----------------
extern "C" void kernel_launch(void* const* d_in, const int* in_sizes, int n_in,
                              void* d_out, int out_size, void* d_ws, size_t ws_size,
                              hipStream_t stream)
{
    const float* node_feats = (const float*)d_in[0];
    const int*   adj        = (const int*)d_in[1];
    const float* dist       = (const float*)d_in[2];
    const float* eoh        = (const float*)d_in[3];
    const float* npw        = (const float*)d_in[4];
    const float* npb        = (const float*)d_in[5];
    const float* cls        = (const float*)d_in[6];
    const float* etw        = (const float*)d_in[7];
    const float* noedge     = (const float*)d_in[8];
    const float* degsc      = (const float*)d_in[9];
    const float* gamma      = (const float*)d_in[10];
    const float* v2n        = (const float*)d_in[11];
    const float* n2v        = (const float*)d_in[12];
    const float* vself      = (const float*)d_in[13];
    const float* ln1g = (const float*)d_in[14];
    const float* ln1b = (const float*)d_in[15];
    const float* qw   = (const float*)d_in[16];
    const float* qb   = (const float*)d_in[17];
    const float* kw   = (const float*)d_in[18];
    const float* kb   = (const float*)d_in[19];
    const float* vw   = (const float*)d_in[20];
    const float* vb   = (const float*)d_in[21];
    const float* ow   = (const float*)d_in[22];
    const float* ob   = (const float*)d_in[23];
    const float* ln2g = (const float*)d_in[24];
    const float* ln2b = (const float*)d_in[25];
    const float* f1w  = (const float*)d_in[26];
    const float* f1b  = (const float*)d_in[27];
    const float* f2w  = (const float*)d_in[28];
    const float* f2b  = (const float*)d_in[29];

    float* x  = (float*)d_out;   // (B,T,D) lives in d_out
    float* ws = (float*)d_ws;
    size_t off = 0;
    float* bias = ws + off; off += (size_t)BB * TT * TT;   // 4,730,888
    float* deg  = ws + off; off += (size_t)BB * NN;
    float* dmax = ws + off; off += 8;
    float* xn   = ws + off; off += (size_t)BB * TT * DD;
    float* qbuf = ws + off; off += (size_t)BB * TT * DD;
    float* kbuf = ws + off; off += (size_t)BB * TT * DD;
    float* vbuf = ws + off; off += (size_t)BB * TT * DD;
    float* abuf = ws + off; off += (size_t)BB * TT * DD;
    float* hbuf = ws + off; off += (size_t)BB * TT * DD;
    // total ~56.8 MB of f32 workspace

    const int M = BB * TT;   // 6152

    deg_kernel<<<BB * NN / 4 / 64, 256, 0, stream>>>(adj, deg);   // 6144 rows / 4 per block = 1536... 
    degmax_kernel<<<BB, 256, 0, stream>>>(deg, dmax);

    long long total = (long long)BB * TT * TT;
    bias_kernel<<<(int)((total + 255) / 256), 256, 0, stream>>>(
        dist, eoh, adj, deg, dmax, etw, noedge, degsc, gamma, v2n, n2v, vself, bias);

    nodeproj_kernel<<<M, 256, 0, stream>>>(node_feats, npw, npb, cls, x);

    dim3 gg((M + 63) / 64, 4);
    dim3 ga((TT + QT - 1) / QT, HH, BB);
    for (int l = 0; l < LL; ++l) {
        size_t wo = (size_t)l * DD * DD;
        size_t bo = (size_t)l * DD;
        ln_kernel<<<M, 256, 0, stream>>>(x, ln1g + bo, ln1b + bo, xn);
        gemm256_kernel<<<gg, 256, 0, stream>>>(xn, qw + wo, qb + bo, nullptr, qbuf, M, 0);
        gemm256_kernel<<<gg, 256, 0, stream>>>(xn, kw + wo, kb + bo, nullptr, kbuf, M, 0);
        gemm256_kernel<<<gg, 256, 0, stream>>>(xn, vw + wo, vb + bo, nullptr, vbuf, M, 0);
        attn_kernel<<<ga, 256, 0, stream>>>(qbuf, kbuf, vbuf, bias, abuf);
        gemm256_kernel<<<gg, 256, 0, stream>>>(abuf, ow + wo, ob + bo, x, x, M, 0);
        ln_kernel<<<M, 256, 0, stream>>>(x, ln2g + bo, ln2b + bo, xn);
        gemm256_kernel<<<gg, 256, 0, stream>>>(xn, f1w + wo, f1b + bo, nullptr, hbuf, M, 1);
        gemm256_kernel<<<gg, 256, 0, stream>>>(hbuf, f2w + wo, f2b + bo, x, x, M, 0);
    }
}

// Round 2
// 1839.979 us; speedup vs baseline: 1.4865x; 1.4865x over previous
//
#include <hip/hip_runtime.h>
#include <math.h>

#define BB 8
#define NN 768
#define TT 769
#define DD 256
#define HH 8
#define DKK 32
#define FF 128
#define LL 6
#define SCALE 0.17677669529663687f   // 1/sqrt(32)
#define TP 800                       // vt row pitch (keys, padded 769->800)

typedef __attribute__((ext_vector_type(8))) short s16x8;
typedef __attribute__((ext_vector_type(4))) float f32x4;

__device__ inline short f2bf(float x) {
    unsigned u = __float_as_uint(x);
    unsigned r = (u + 0x7FFFu + ((u >> 16) & 1u)) >> 16;   // RNE
    return (short)r;
}

// ---------------- degree: deg[b,i] = sum_j adj[b,i,j] ----------------
__global__ __launch_bounds__(256) void deg_kernel(const int* __restrict__ adj,
                                                  float* __restrict__ deg) {
    int row  = blockIdx.x * 4 + (threadIdx.x >> 6);   // 0..6143 (b*NN+i)
    int lane = threadIdx.x & 63;
    const int* p = adj + (size_t)row * NN;
    int s = 0;
#pragma unroll
    for (int i = 0; i < NN / 64; ++i) s += p[lane + 64 * i];
#pragma unroll
    for (int off = 32; off > 0; off >>= 1) s += __shfl_xor(s, off);
    if (lane == 0) deg[row] = (float)s;
}

__global__ __launch_bounds__(256) void degmax_kernel(const float* __restrict__ deg,
                                                     float* __restrict__ dmax) {
    __shared__ float red[256];
    int b = blockIdx.x, t = threadIdx.x;
    float m = 0.f;
    for (int i = t; i < NN; i += 256) m = fmaxf(m, deg[b * NN + i]);
    red[t] = m;
    __syncthreads();
    for (int s = 128; s > 0; s >>= 1) {
        if (t < s) red[t] = fmaxf(red[t], red[t + s]);
        __syncthreads();
    }
    if (t == 0) dmax[b] = red[0];
}

// ---------------- attention bias (B,T,T) ----------------
__global__ __launch_bounds__(256) void bias_kernel(
    const float* __restrict__ dist, const float* __restrict__ eoh,
    const int* __restrict__ adj, const float* __restrict__ deg,
    const float* __restrict__ dmax, const float* __restrict__ etw,
    const float* __restrict__ noedge, const float* __restrict__ degsc,
    const float* __restrict__ gamma, const float* __restrict__ v2n,
    const float* __restrict__ n2v, const float* __restrict__ vself,
    float* __restrict__ bias)
{
    long long idx = (long long)blockIdx.x * 256 + threadIdx.x;
    const long long total = (long long)BB * TT * TT;
    if (idx >= total) return;
    int b  = (int)(idx / ((long long)TT * TT));
    int r  = (int)(idx % ((long long)TT * TT));
    int qi = r / TT, kj = r % TT;
    float out;
    if (qi == 0 && kj == 0) out = vself[0];
    else if (qi == 0)       out = v2n[0];
    else if (kj == 0)       out = n2v[0];
    else {
        int i = qi - 1, j = kj - 1;
        size_t e = ((size_t)b * NN + i) * NN + j;
        float4 oh = *(const float4*)(eoh + 4 * e);
        float val = oh.x * etw[0] + oh.y * etw[1] + oh.z * etw[2] + oh.w * etw[3]
                    - gamma[0] * dist[e];
        if (adj[e] == 0) val += noedge[0];
        val += degsc[0] * (deg[b * NN + i] + deg[b * NN + j]) / (dmax[b] + 1e-6f);
        out = val;
    }
    bias[idx] = out;
}

// ---------------- node projection + cls row -> x (lives in d_out) ----------------
__global__ __launch_bounds__(256) void nodeproj_kernel(
    const float* __restrict__ nf, const float* __restrict__ w,
    const float* __restrict__ bsv, const float* __restrict__ cls,
    float* __restrict__ x)
{
    int row = blockIdx.x;   // 0..6151 = b*TT + tr
    int t = threadIdx.x;
    int b = row / TT, tr = row % TT;
    if (tr == 0) { x[(size_t)row * DD + t] = cls[t]; return; }
    __shared__ float sf[FF];
    int i = tr - 1;
    if (t < FF) sf[t] = nf[((size_t)b * NN + i) * FF + t];
    __syncthreads();
    float acc = bsv[t];
#pragma unroll 8
    for (int k = 0; k < FF; ++k) acc = fmaf(sf[k], w[k * DD + t], acc);
    x[(size_t)row * DD + t] = acc;
}

// ---------------- layernorm (one row per block, D=256) ----------------
__global__ __launch_bounds__(256) void ln_kernel(
    const float* __restrict__ x, const float* __restrict__ g,
    const float* __restrict__ bsv, float* __restrict__ out)
{
    __shared__ float red[256];
    int row = blockIdx.x, t = threadIdx.x;
    float v = x[(size_t)row * DD + t];
    red[t] = v;
    __syncthreads();
    for (int s = 128; s > 0; s >>= 1) { if (t < s) red[t] += red[t + s]; __syncthreads(); }
    float mean = red[0] * (1.f / DD);
    __syncthreads();
    float d = v - mean;
    red[t] = d * d;
    __syncthreads();
    for (int s = 128; s > 0; s >>= 1) { if (t < s) red[t] += red[t + s]; __syncthreads(); }
    float var = red[0] * (1.f / DD);
    out[(size_t)row * DD + t] = d * rsqrtf(var + 1e-5f) * g[t] + bsv[t];
}

// ---------------- generic f32 GEMM: C = act(A(Mx256) @ W(256x256) + bias) ----------------
// omode: 0 = f32 out (+resid), 1 = gelu f32 out (+resid), 2 = bf16 out
__device__ inline float gelu_f(float x) {
    return 0.5f * x * (1.f + erff(x * 0.70710678118654752f));
}

__global__ __launch_bounds__(256) void gemm256_kernel(
    const float* __restrict__ A, const float* __restrict__ W,
    const float* __restrict__ bsv, const float* __restrict__ resid,
    void* __restrict__ Cv, int M, int omode)
{
    __shared__ float As[16][64];   // [k][m]
    __shared__ float Ws[16][64];   // [k][n]
    int t  = threadIdx.x;
    int tx = t & 15, ty = t >> 4;
    int m0 = blockIdx.x * 64, n0 = blockIdx.y * 64;
    int lm = t >> 2, lk = (t & 3) * 4;
    int wr = t >> 4, wc = (t & 15) * 4;
    float acc[4][4] = {};
    for (int k0 = 0; k0 < DD; k0 += 16) {
        float4 av = make_float4(0.f, 0.f, 0.f, 0.f);
        if (m0 + lm < M) av = *(const float4*)(A + (size_t)(m0 + lm) * DD + k0 + lk);
        As[lk + 0][lm] = av.x; As[lk + 1][lm] = av.y;
        As[lk + 2][lm] = av.z; As[lk + 3][lm] = av.w;
        *(float4*)&Ws[wr][wc] = *(const float4*)(W + (size_t)(k0 + wr) * DD + n0 + wc);
        __syncthreads();
#pragma unroll
        for (int kk = 0; kk < 16; ++kk) {
            float4 a4 = *(const float4*)&As[kk][ty * 4];
            float4 w4 = *(const float4*)&Ws[kk][tx * 4];
            float ar[4] = {a4.x, a4.y, a4.z, a4.w};
            float wr4[4] = {w4.x, w4.y, w4.z, w4.w};
#pragma unroll
            for (int r = 0; r < 4; ++r)
#pragma unroll
                for (int c = 0; c < 4; ++c)
                    acc[r][c] = fmaf(ar[r], wr4[c], acc[r][c]);
        }
        __syncthreads();
    }
#pragma unroll
    for (int r = 0; r < 4; ++r) {
        int row = m0 + ty * 4 + r;
        if (row >= M) continue;
#pragma unroll
        for (int c = 0; c < 4; ++c) {
            int col = n0 + tx * 4 + c;
            float v = acc[r][c] + bsv[col];
            if (omode == 1) v = gelu_f(v);
            if (resid) v += resid[(size_t)row * DD + col];
            size_t idx = (size_t)row * DD + col;
            if (omode == 2) ((short*)Cv)[idx] = f2bf(v);
            else            ((float*)Cv)[idx] = v;
        }
    }
}

// ---------------- V transpose+repack: vbuf bf16 (B,T,256) -> vt bf16 (B,H,32,TP) ----------------
__global__ __launch_bounds__(256) void vtrans_kernel(const short* __restrict__ v,
                                                     short* __restrict__ vt)
{
    __shared__ short tile[32][33];
    int b = blockIdx.z, h = blockIdx.y, t0 = blockIdx.x * 32;
    int dk = threadIdx.x & 31, tr = threadIdx.x >> 5;   // tr = 0..7
#pragma unroll
    for (int i = 0; i < 4; ++i) {
        int tl = tr + i * 8;
        int tt = t0 + tl;
        short val = 0;
        if (tt < TT) val = v[((size_t)(b * TT + tt)) * DD + h * DKK + dk];
        tile[tl][dk] = val;
    }
    __syncthreads();
    int tl = threadIdx.x & 31, dko = threadIdx.x >> 5;  // dko = 0..7
#pragma unroll
    for (int i = 0; i < 4; ++i) {
        int d = dko + i * 8;
        vt[(((size_t)(b * HH + h)) * DKK + d) * TP + t0 + tl] = tile[tl][d];
    }
}

// ---------------- flash attention, MFMA bf16 16x16x32 ----------------
// grid (13, H, B), block 256 (4 waves x 16 q-rows); q,k bf16 (B,T,256); vt (B,H,32,TP)
__global__ __launch_bounds__(256) void attn_mfma_kernel(
    const short* __restrict__ q, const short* __restrict__ k,
    const short* __restrict__ vt, const float* __restrict__ bias,
    float* __restrict__ o)
{
    __shared__ short Pb[4][16][40];   // per-wave P buffer, C-layout -> A-layout
    int t = threadIdx.x;
    int wid = t >> 6, lane = t & 63;
    int quad = lane >> 4, m16 = lane & 15;
    int b = blockIdx.z, h = blockIdx.y;
    int q0 = blockIdx.x * 64 + wid * 16;

    // Q A-frag: lane holds Q[q0 + (lane&15)][quad*8 + j]
    int qrow = q0 + m16;
    int qc = qrow < TT ? qrow : TT - 1;
    s16x8 qa = *(const s16x8*)(q + ((size_t)(b * TT + qc)) * DD + h * DKK + quad * 8);

    f32x4 oacc0 = {0.f, 0.f, 0.f, 0.f};   // dk 0..15, rows quad*4+reg
    f32x4 oacc1 = {0.f, 0.f, 0.f, 0.f};   // dk 16..31
    float mrow[4], lrow[4];
#pragma unroll
    for (int r = 0; r < 4; ++r) { mrow[r] = -1e30f; lrow[r] = 0.f; }

    // bias row pointers for this lane's 4 output rows (clamped)
    const float* brows[4];
#pragma unroll
    for (int r = 0; r < 4; ++r) {
        int qr = q0 + quad * 4 + r;
        int qcl = qr < TT ? qr : TT - 1;
        brows[r] = bias + ((size_t)b * TT + qcl) * TT;
    }
    const short* kbase = k + ((size_t)(b * TT)) * DD + h * DKK + quad * 8;
    const short* vbase = vt + (((size_t)(b * HH + h)) * DKK) * TP;

    for (int j0 = 0; j0 < 800; j0 += 32) {
        // ---- S = Q K^T for two 16-key tiles ----
        int kr0 = j0 + m16;       int kc0 = kr0 < TT ? kr0 : TT - 1;
        int kr1 = j0 + 16 + m16;  int kc1 = kr1 < TT ? kr1 : TT - 1;
        s16x8 ka0 = *(const s16x8*)(kbase + (size_t)kc0 * DD);
        s16x8 ka1 = *(const s16x8*)(kbase + (size_t)kc1 * DD);
        f32x4 z = {0.f, 0.f, 0.f, 0.f};
        f32x4 s0 = __builtin_amdgcn_mfma_f32_16x16x32_bf16(qa, ka0, z, 0, 0, 0);
        f32x4 s1 = __builtin_amdgcn_mfma_f32_16x16x32_bf16(qa, ka1, z, 0, 0, 0);

        // ---- bias + scale + mask (C-layout: row=quad*4+r, col=m16) ----
        int key0 = j0 + m16, key1 = j0 + 16 + m16;
        int k0v = key0 < TT, k1v = key1 < TT;
        int k0c = k0v ? key0 : TT - 1, k1c = k1v ? key1 : TT - 1;
        float sv[8];
#pragma unroll
        for (int r = 0; r < 4; ++r) {
            float b0 = brows[r][k0c];
            float b1 = brows[r][k1c];
            sv[r]     = k0v ? s0[r] * SCALE + b0 : -1e30f;
            sv[4 + r] = k1v ? s1[r] * SCALE + b1 : -1e30f;
        }

        // ---- online softmax (rows live across 16 lanes of each quad) ----
#pragma unroll
        for (int r = 0; r < 4; ++r) {
            float mx = fmaxf(sv[r], sv[4 + r]);
#pragma unroll
            for (int off = 1; off < 16; off <<= 1) mx = fmaxf(mx, __shfl_xor(mx, off));
            float mnew = fmaxf(mrow[r], mx);
            float alpha = __expf(mrow[r] - mnew);
            mrow[r] = mnew;
            float p0 = __expf(sv[r] - mnew);
            float p1 = __expf(sv[4 + r] - mnew);
            float ps = p0 + p1;
#pragma unroll
            for (int off = 1; off < 16; off <<= 1) ps += __shfl_xor(ps, off);
            lrow[r] = lrow[r] * alpha + ps;
            oacc0[r] *= alpha; oacc1[r] *= alpha;
            sv[r] = p0; sv[4 + r] = p1;
        }

        // ---- P: C-layout -> A-layout via wave-private LDS ----
        __syncthreads();   // WAR vs previous chunk's reads
#pragma unroll
        for (int r = 0; r < 4; ++r) {
            Pb[wid][quad * 4 + r][m16]      = f2bf(sv[r]);
            Pb[wid][quad * 4 + r][16 + m16] = f2bf(sv[4 + r]);
        }
        __syncthreads();
        s16x8 pa = *(const s16x8*)(&Pb[wid][m16][quad * 8]);

        // ---- O += P V (two dk halves); B-frag from pre-transposed vt ----
        s16x8 va0 = *(const s16x8*)(vbase + (size_t)m16 * TP + j0 + quad * 8);
        s16x8 va1 = *(const s16x8*)(vbase + (size_t)(16 + m16) * TP + j0 + quad * 8);
        oacc0 = __builtin_amdgcn_mfma_f32_16x16x32_bf16(pa, va0, oacc0, 0, 0, 0);
        oacc1 = __builtin_amdgcn_mfma_f32_16x16x32_bf16(pa, va1, oacc1, 0, 0, 0);
    }

    // ---- store O rows ----
#pragma unroll
    for (int r = 0; r < 4; ++r) {
        int qr = q0 + quad * 4 + r;
        if (qr < TT) {
            float inv = 1.f / lrow[r];
            float* op = o + ((size_t)(b * TT + qr)) * DD + h * DKK;
            op[m16]      = oacc0[r] * inv;
            op[16 + m16] = oacc1[r] * inv;
        }
    }
}

// ---------------- host ----------------
extern "C" void kernel_launch(void* const* d_in, const int* in_sizes, int n_in,
                              void* d_out, int out_size, void* d_ws, size_t ws_size,
                              hipStream_t stream)
{
    const float* node_feats = (const float*)d_in[0];
    const int*   adj        = (const int*)d_in[1];
    const float* dist       = (const float*)d_in[2];
    const float* eoh        = (const float*)d_in[3];
    const float* npw        = (const float*)d_in[4];
    const float* npb        = (const float*)d_in[5];
    const float* cls        = (const float*)d_in[6];
    const float* etw        = (const float*)d_in[7];
    const float* noedge     = (const float*)d_in[8];
    const float* degsc      = (const float*)d_in[9];
    const float* gamma      = (const float*)d_in[10];
    const float* v2n        = (const float*)d_in[11];
    const float* n2v        = (const float*)d_in[12];
    const float* vself      = (const float*)d_in[13];
    const float* ln1g = (const float*)d_in[14];
    const float* ln1b = (const float*)d_in[15];
    const float* qw   = (const float*)d_in[16];
    const float* qb   = (const float*)d_in[17];
    const float* kw   = (const float*)d_in[18];
    const float* kb   = (const float*)d_in[19];
    const float* vw   = (const float*)d_in[20];
    const float* vb   = (const float*)d_in[21];
    const float* ow   = (const float*)d_in[22];
    const float* ob   = (const float*)d_in[23];
    const float* ln2g = (const float*)d_in[24];
    const float* ln2b = (const float*)d_in[25];
    const float* f1w  = (const float*)d_in[26];
    const float* f1b  = (const float*)d_in[27];
    const float* f2w  = (const float*)d_in[28];
    const float* f2b  = (const float*)d_in[29];

    float* x  = (float*)d_out;   // (B,T,D) lives in d_out
    float* ws = (float*)d_ws;
    size_t off = 0;
    float* bias = ws + off; off += (size_t)BB * TT * TT;          // 4,730,888 f
    float* deg  = ws + off; off += (size_t)BB * NN;
    float* dmax = ws + off; off += 8;
    float* xn   = ws + off; off += (size_t)BB * TT * DD;          // f32
    short* qb16 = (short*)(ws + off); off += (size_t)BB * TT * DD / 2;
    short* kb16 = (short*)(ws + off); off += (size_t)BB * TT * DD / 2;
    short* vb16 = (short*)(ws + off); off += (size_t)BB * TT * DD / 2;
    short* vtb  = (short*)(ws + off); off += (size_t)BB * HH * DKK * TP / 2;
    float* abuf = ws + off; off += (size_t)BB * TT * DD;
    float* hbuf = ws + off; off += (size_t)BB * TT * DD;
    // ~51 MB total

    const int M = BB * TT;   // 6152

    deg_kernel<<<(BB * NN) / 4, 256, 0, stream>>>(adj, deg);   // 1536 blocks x 4 rows
    degmax_kernel<<<BB, 256, 0, stream>>>(deg, dmax);

    long long total = (long long)BB * TT * TT;
    bias_kernel<<<(int)((total + 255) / 256), 256, 0, stream>>>(
        dist, eoh, adj, deg, dmax, etw, noedge, degsc, gamma, v2n, n2v, vself, bias);

    nodeproj_kernel<<<M, 256, 0, stream>>>(node_feats, npw, npb, cls, x);

    dim3 gg((M + 63) / 64, 4);
    dim3 ga(13, HH, BB);
    dim3 gvt(25, HH, BB);
    for (int l = 0; l < LL; ++l) {
        size_t wo = (size_t)l * DD * DD;
        size_t bo = (size_t)l * DD;
        ln_kernel<<<M, 256, 0, stream>>>(x, ln1g + bo, ln1b + bo, xn);
        gemm256_kernel<<<gg, 256, 0, stream>>>(xn, qw + wo, qb + bo, nullptr, qb16, M, 2);
        gemm256_kernel<<<gg, 256, 0, stream>>>(xn, kw + wo, kb + bo, nullptr, kb16, M, 2);
        gemm256_kernel<<<gg, 256, 0, stream>>>(xn, vw + wo, vb + bo, nullptr, vb16, M, 2);
        vtrans_kernel<<<gvt, 256, 0, stream>>>(vb16, vtb);
        attn_mfma_kernel<<<ga, 256, 0, stream>>>(qb16, kb16, vtb, bias, abuf);
        gemm256_kernel<<<gg, 256, 0, stream>>>(abuf, ow + wo, ob + bo, x, x, M, 0);
        ln_kernel<<<M, 256, 0, stream>>>(x, ln2g + bo, ln2b + bo, xn);
        gemm256_kernel<<<gg, 256, 0, stream>>>(xn, f1w + wo, f1b + bo, nullptr, hbuf, M, 1);
        gemm256_kernel<<<gg, 256, 0, stream>>>(hbuf, f2w + wo, f2b + bo, x, x, M, 0);
    }
}

// Round 3
// 1091.114 us; speedup vs baseline: 2.5068x; 1.6863x over previous
//
#include <hip/hip_runtime.h>
#include <math.h>

#define BB 8
#define NN 768
#define TT 769
#define DD 256
#define HH 8
#define DKK 32
#define FF 128
#define LL 6
#define SCALE 0.17677669529663687f   // 1/sqrt(32)
#define TP 832                       // vt row pitch (keys padded 769->832)
#define NCH 13                       // 13 x 64-key chunks

typedef __attribute__((ext_vector_type(8))) short s16x8;
typedef __attribute__((ext_vector_type(4))) float f32x4;

__device__ inline short f2bf(float x) {
    unsigned u = __float_as_uint(x);
    unsigned r = (u + 0x7FFFu + ((u >> 16) & 1u)) >> 16;   // RNE
    return (short)r;
}

// ---------------- degree ----------------
__global__ __launch_bounds__(256) void deg_kernel(const int* __restrict__ adj,
                                                  float* __restrict__ deg) {
    int row  = blockIdx.x * 4 + (threadIdx.x >> 6);
    int lane = threadIdx.x & 63;
    const int* p = adj + (size_t)row * NN;
    int s = 0;
#pragma unroll
    for (int i = 0; i < NN / 64; ++i) s += p[lane + 64 * i];
#pragma unroll
    for (int off = 32; off > 0; off >>= 1) s += __shfl_xor(s, off);
    if (lane == 0) deg[row] = (float)s;
}

__global__ __launch_bounds__(256) void degmax_kernel(const float* __restrict__ deg,
                                                     float* __restrict__ dmax) {
    __shared__ float red[256];
    int b = blockIdx.x, t = threadIdx.x;
    float m = 0.f;
    for (int i = t; i < NN; i += 256) m = fmaxf(m, deg[b * NN + i]);
    red[t] = m;
    __syncthreads();
    for (int s = 128; s > 0; s >>= 1) {
        if (t < s) red[t] = fmaxf(red[t], red[t + s]);
        __syncthreads();
    }
    if (t == 0) dmax[b] = red[0];
}

// ---------------- attention bias (B,T,T) f32 ----------------
__global__ __launch_bounds__(256) void bias_kernel(
    const float* __restrict__ dist, const float* __restrict__ eoh,
    const int* __restrict__ adj, const float* __restrict__ deg,
    const float* __restrict__ dmax, const float* __restrict__ etw,
    const float* __restrict__ noedge, const float* __restrict__ degsc,
    const float* __restrict__ gamma, const float* __restrict__ v2n,
    const float* __restrict__ n2v, const float* __restrict__ vself,
    float* __restrict__ bias)
{
    long long idx = (long long)blockIdx.x * 256 + threadIdx.x;
    const long long total = (long long)BB * TT * TT;
    if (idx >= total) return;
    int b  = (int)(idx / ((long long)TT * TT));
    int r  = (int)(idx % ((long long)TT * TT));
    int qi = r / TT, kj = r % TT;
    float out;
    if (qi == 0 && kj == 0) out = vself[0];
    else if (qi == 0)       out = v2n[0];
    else if (kj == 0)       out = n2v[0];
    else {
        int i = qi - 1, j = kj - 1;
        size_t e = ((size_t)b * NN + i) * NN + j;
        float4 oh = *(const float4*)(eoh + 4 * e);
        float val = oh.x * etw[0] + oh.y * etw[1] + oh.z * etw[2] + oh.w * etw[3]
                    - gamma[0] * dist[e];
        if (adj[e] == 0) val += noedge[0];
        val += degsc[0] * (deg[b * NN + i] + deg[b * NN + j]) / (dmax[b] + 1e-6f);
        out = val;
    }
    bias[idx] = out;
}

// ---------------- node projection + cls (writes f32 x in d_out) ----------------
__global__ __launch_bounds__(256) void nodeproj_kernel(
    const float* __restrict__ nf, const float* __restrict__ w,
    const float* __restrict__ bsv, const float* __restrict__ cls,
    float* __restrict__ x)
{
    int row = blockIdx.x;
    int t = threadIdx.x;
    int b = row / TT, tr = row % TT;
    if (tr == 0) { x[(size_t)row * DD + t] = cls[t]; return; }
    __shared__ float sf[FF];
    int i = tr - 1;
    if (t < FF) sf[t] = nf[((size_t)b * NN + i) * FF + t];
    __syncthreads();
    float acc = bsv[t];
#pragma unroll 8
    for (int k = 0; k < FF; ++k) acc = fmaf(sf[k], w[k * DD + t], acc);
    x[(size_t)row * DD + t] = acc;
}

// ---------------- layernorm -> bf16 ----------------
__global__ __launch_bounds__(256) void ln_kernel(
    const float* __restrict__ x, const float* __restrict__ g,
    const float* __restrict__ bsv, short* __restrict__ out)
{
    __shared__ float red[256];
    int row = blockIdx.x, t = threadIdx.x;
    float v = x[(size_t)row * DD + t];
    red[t] = v;
    __syncthreads();
    for (int s = 128; s > 0; s >>= 1) { if (t < s) red[t] += red[t + s]; __syncthreads(); }
    float mean = red[0] * (1.f / DD);
    __syncthreads();
    float d = v - mean;
    red[t] = d * d;
    __syncthreads();
    for (int s = 128; s > 0; s >>= 1) { if (t < s) red[t] += red[t + s]; __syncthreads(); }
    float var = red[0] * (1.f / DD);
    out[(size_t)row * DD + t] = f2bf(d * rsqrtf(var + 1e-5f) * g[t] + bsv[t]);
}

// ---------------- weight transpose+cast: 36 x (256,256) f32 -> bf16 W^T ----------------
__global__ __launch_bounds__(256) void wtrans_kernel(
    const float* __restrict__ qw, const float* __restrict__ kw,
    const float* __restrict__ vw, const float* __restrict__ ow,
    const float* __restrict__ f1w, const float* __restrict__ f2w,
    short* __restrict__ wt)
{
    __shared__ short tile[64][72];
    int mi = blockIdx.z;              // family*6 + layer
    int fam = mi / 6, l = mi % 6;
    const float* W;
    if      (fam == 0) W = qw;
    else if (fam == 1) W = kw;
    else if (fam == 2) W = vw;
    else if (fam == 3) W = ow;
    else if (fam == 4) W = f1w;
    else               W = f2w;
    W += (size_t)l * DD * DD;
    int k0 = blockIdx.x * 64, n0 = blockIdx.y * 64;
    int t = threadIdx.x;
    int r = t >> 2, cs = (t & 3) * 16;
#pragma unroll
    for (int i = 0; i < 4; ++i) {
        float4 v4 = *(const float4*)(W + (size_t)(k0 + r) * DD + n0 + cs + i * 4);
        tile[r][cs + i * 4 + 0] = f2bf(v4.x);
        tile[r][cs + i * 4 + 1] = f2bf(v4.y);
        tile[r][cs + i * 4 + 2] = f2bf(v4.z);
        tile[r][cs + i * 4 + 3] = f2bf(v4.w);
    }
    __syncthreads();
    int nl = t >> 2, ks = (t & 3) * 16;
    short* op = wt + (size_t)mi * DD * DD + (size_t)(n0 + nl) * DD + k0 + ks;
#pragma unroll
    for (int j = 0; j < 16; ++j) op[j] = tile[ks + j][nl];
}

// ---------------- bf16 MFMA GEMM: out = act(A(Mx256) @ W + bias) [+resid] ----------------
// Wt is W^T bf16 (n,k). omode: 0 = bf16 out, 1 = f32 out + resid, 2 = gelu bf16 out
__device__ inline float gelu_f(float x) {
    return 0.5f * x * (1.f + erff(x * 0.70710678118654752f));
}

__global__ __launch_bounds__(256) void gemm_mfma_kernel(
    const short* __restrict__ A, const short* __restrict__ Wt,
    const float* __restrict__ bsv, const float* __restrict__ resid,
    void* __restrict__ out, int M, int omode)
{
    __shared__ short As[64][40];
    __shared__ short Bs[64][40];
    int t = threadIdx.x;
    int wv = t >> 6, lane = t & 63, quad = lane >> 4, m16 = lane & 15;
    int m0 = blockIdx.x * 64, n0 = blockIdx.y * 64;
    int lr = t >> 2, lc = (t & 3) * 8;
    int arow = m0 + lr; if (arow >= M) arow = M - 1;
    const short* aptr = A + (size_t)arow * DD + lc;
    const short* bptr = Wt + (size_t)(n0 + lr) * DD + lc;
    f32x4 acc[4] = {};
    for (int k0 = 0; k0 < DD; k0 += 32) {
        *(s16x8*)&As[lr][lc] = *(const s16x8*)(aptr + k0);
        *(s16x8*)&Bs[lr][lc] = *(const s16x8*)(bptr + k0);
        __syncthreads();
        s16x8 bf = *(const s16x8*)&Bs[wv * 16 + m16][quad * 8];
#pragma unroll
        for (int mt = 0; mt < 4; ++mt) {
            s16x8 af = *(const s16x8*)&As[mt * 16 + m16][quad * 8];
            acc[mt] = __builtin_amdgcn_mfma_f32_16x16x32_bf16(af, bf, acc[mt], 0, 0, 0);
        }
        __syncthreads();
    }
    int col = n0 + wv * 16 + m16;
    float bv = bsv[col];
#pragma unroll
    for (int mt = 0; mt < 4; ++mt) {
#pragma unroll
        for (int r = 0; r < 4; ++r) {
            int row = m0 + mt * 16 + quad * 4 + r;
            if (row >= M) continue;
            float v = acc[mt][r] + bv;
            size_t idx = (size_t)row * DD + col;
            if (omode == 2) v = gelu_f(v);
            if (omode == 1) ((float*)out)[idx] = v + resid[idx];
            else            ((short*)out)[idx] = f2bf(v);
        }
    }
}

// ---------------- V transpose: vb16 (B,T,256) -> vt (B,H,32,TP) ----------------
__global__ __launch_bounds__(256) void vtrans_kernel(const short* __restrict__ v,
                                                     short* __restrict__ vt)
{
    __shared__ short tile[32][33];
    int b = blockIdx.z, h = blockIdx.y, t0 = blockIdx.x * 32;
    int dk = threadIdx.x & 31, tr = threadIdx.x >> 5;
#pragma unroll
    for (int i = 0; i < 4; ++i) {
        int tl = tr + i * 8;
        int tt = t0 + tl;
        short val = 0;
        if (tt < TT) val = v[((size_t)(b * TT + tt)) * DD + h * DKK + dk];
        tile[tl][dk] = val;
    }
    __syncthreads();
    int tl = threadIdx.x & 31, dko = threadIdx.x >> 5;
#pragma unroll
    for (int i = 0; i < 4; ++i) {
        int d = dko + i * 8;
        vt[(((size_t)(b * HH + h)) * DKK + d) * TP + t0 + tl] = tile[tl][d];
    }
}

// ---------------- flash attention MFMA, 64-key chunks, barrier-free, prefetch ----------------
__global__ __launch_bounds__(256) void attn_mfma_kernel(
    const short* __restrict__ q, const short* __restrict__ k,
    const short* __restrict__ vt, const float* __restrict__ bias,
    short* __restrict__ o)
{
    __shared__ short Pb[4][16][72];   // per-wave P buffer (wave-private: no barriers)
    int t = threadIdx.x;
    int wid = t >> 6, lane = t & 63;
    int quad = lane >> 4, m16 = lane & 15;
    int b = blockIdx.z, h = blockIdx.y;
    int q0 = blockIdx.x * 64 + wid * 16;

    int qrow = q0 + m16;
    int qc = qrow < TT ? qrow : TT - 1;
    s16x8 qa = *(const s16x8*)(q + ((size_t)(b * TT + qc)) * DD + h * DKK + quad * 8);

    f32x4 oacc0 = {0.f, 0.f, 0.f, 0.f};
    f32x4 oacc1 = {0.f, 0.f, 0.f, 0.f};
    float mrow[4], lsum[4];
#pragma unroll
    for (int r = 0; r < 4; ++r) { mrow[r] = -1e30f; lsum[r] = 0.f; }

    const float* brows[4];
#pragma unroll
    for (int r = 0; r < 4; ++r) {
        int qr = q0 + quad * 4 + r;
        brows[r] = bias + ((size_t)b * TT + (qr < TT ? qr : TT - 1)) * TT;
    }
    const short* kbase = k + ((size_t)(b * TT)) * DD + h * DKK + quad * 8;
    const short* vbase = vt + (((size_t)(b * HH + h)) * DKK) * TP;

    // prefetch chunk 0 (K frags + bias)
    s16x8 kc[4], kn[4];
    float bc[16], bn[16];
#pragma unroll
    for (int s = 0; s < 4; ++s) {
        int kr = s * 16 + m16;
        int kcl = kr < TT ? kr : TT - 1;
        kc[s] = *(const s16x8*)(kbase + (size_t)kcl * DD);
#pragma unroll
        for (int r = 0; r < 4; ++r) bc[s * 4 + r] = brows[r][kcl];
    }

    for (int c = 0; c < NCH; ++c) {
        int j0 = c * 64;
        if (c + 1 < NCH) {
            int jn = j0 + 64;
#pragma unroll
            for (int s = 0; s < 4; ++s) {
                int kr = jn + s * 16 + m16;
                int kcl = kr < TT ? kr : TT - 1;
                kn[s] = *(const s16x8*)(kbase + (size_t)kcl * DD);
#pragma unroll
                for (int r = 0; r < 4; ++r) bn[s * 4 + r] = brows[r][kcl];
            }
        }
        // S = Q K^T (4 x 16-key tiles)
        f32x4 z = {0.f, 0.f, 0.f, 0.f};
        f32x4 sacc[4];
#pragma unroll
        for (int s = 0; s < 4; ++s)
            sacc[s] = __builtin_amdgcn_mfma_f32_16x16x32_bf16(qa, kc[s], z, 0, 0, 0);

        float sv[16];
#pragma unroll
        for (int s = 0; s < 4; ++s) {
            int key = j0 + s * 16 + m16;
            int kvld = key < TT;
#pragma unroll
            for (int r = 0; r < 4; ++r)
                sv[s * 4 + r] = kvld ? sacc[s][r] * SCALE + bc[s * 4 + r] : -1e30f;
        }

        // online softmax: per-chunk max reduce only (sum deferred per-lane)
#pragma unroll
        for (int r = 0; r < 4; ++r) {
            float mx = fmaxf(fmaxf(sv[r], sv[4 + r]), fmaxf(sv[8 + r], sv[12 + r]));
#pragma unroll
            for (int off = 1; off < 16; off <<= 1) mx = fmaxf(mx, __shfl_xor(mx, off));
            float mnew = fmaxf(mrow[r], mx);
            float alpha = __expf(mrow[r] - mnew);
            mrow[r] = mnew;
            float ps = 0.f;
#pragma unroll
            for (int s = 0; s < 4; ++s) {
                float p = __expf(sv[s * 4 + r] - mnew);
                sv[s * 4 + r] = p;
                ps += p;
            }
            lsum[r] = lsum[r] * alpha + ps;
            oacc0[r] *= alpha; oacc1[r] *= alpha;
        }

        // P: C-layout -> A-layout via wave-private LDS (no block barrier)
#pragma unroll
        for (int s = 0; s < 4; ++s)
#pragma unroll
            for (int r = 0; r < 4; ++r)
                Pb[wid][quad * 4 + r][s * 16 + m16] = f2bf(sv[s * 4 + r]);
        s16x8 pa0 = *(const s16x8*)(&Pb[wid][m16][quad * 8]);
        s16x8 pa1 = *(const s16x8*)(&Pb[wid][m16][32 + quad * 8]);

        // O += P V
        s16x8 va;
        va = *(const s16x8*)(vbase + (size_t)m16 * TP + j0 + quad * 8);
        oacc0 = __builtin_amdgcn_mfma_f32_16x16x32_bf16(pa0, va, oacc0, 0, 0, 0);
        va = *(const s16x8*)(vbase + (size_t)m16 * TP + j0 + 32 + quad * 8);
        oacc0 = __builtin_amdgcn_mfma_f32_16x16x32_bf16(pa1, va, oacc0, 0, 0, 0);
        va = *(const s16x8*)(vbase + (size_t)(16 + m16) * TP + j0 + quad * 8);
        oacc1 = __builtin_amdgcn_mfma_f32_16x16x32_bf16(pa0, va, oacc1, 0, 0, 0);
        va = *(const s16x8*)(vbase + (size_t)(16 + m16) * TP + j0 + 32 + quad * 8);
        oacc1 = __builtin_amdgcn_mfma_f32_16x16x32_bf16(pa1, va, oacc1, 0, 0, 0);

        // rotate prefetch
#pragma unroll
        for (int s = 0; s < 4; ++s) kc[s] = kn[s];
#pragma unroll
        for (int i = 0; i < 16; ++i) bc[i] = bn[i];
    }

    // final l reduce + store O (bf16)
#pragma unroll
    for (int r = 0; r < 4; ++r) {
#pragma unroll
        for (int off = 1; off < 16; off <<= 1) lsum[r] += __shfl_xor(lsum[r], off);
        int qr = q0 + quad * 4 + r;
        if (qr < TT) {
            float inv = 1.f / lsum[r];
            short* op = o + ((size_t)(b * TT + qr)) * DD + h * DKK;
            op[m16]      = f2bf(oacc0[r] * inv);
            op[16 + m16] = f2bf(oacc1[r] * inv);
        }
    }
}

// ---------------- host ----------------
extern "C" void kernel_launch(void* const* d_in, const int* in_sizes, int n_in,
                              void* d_out, int out_size, void* d_ws, size_t ws_size,
                              hipStream_t stream)
{
    const float* node_feats = (const float*)d_in[0];
    const int*   adj        = (const int*)d_in[1];
    const float* dist       = (const float*)d_in[2];
    const float* eoh        = (const float*)d_in[3];
    const float* npw        = (const float*)d_in[4];
    const float* npb        = (const float*)d_in[5];
    const float* cls        = (const float*)d_in[6];
    const float* etw        = (const float*)d_in[7];
    const float* noedge     = (const float*)d_in[8];
    const float* degsc      = (const float*)d_in[9];
    const float* gamma      = (const float*)d_in[10];
    const float* v2n        = (const float*)d_in[11];
    const float* n2v        = (const float*)d_in[12];
    const float* vself      = (const float*)d_in[13];
    const float* ln1g = (const float*)d_in[14];
    const float* ln1b = (const float*)d_in[15];
    const float* qw   = (const float*)d_in[16];
    const float* qb   = (const float*)d_in[17];
    const float* kw   = (const float*)d_in[18];
    const float* kb   = (const float*)d_in[19];
    const float* vw   = (const float*)d_in[20];
    const float* vb   = (const float*)d_in[21];
    const float* ow   = (const float*)d_in[22];
    const float* ob   = (const float*)d_in[23];
    const float* ln2g = (const float*)d_in[24];
    const float* ln2b = (const float*)d_in[25];
    const float* f1w  = (const float*)d_in[26];
    const float* f1b  = (const float*)d_in[27];
    const float* f2w  = (const float*)d_in[28];
    const float* f2b  = (const float*)d_in[29];

    float* x  = (float*)d_out;   // (B,T,D) f32 residual stream
    float* ws = (float*)d_ws;
    size_t off = 0;
    float* bias = ws + off; off += (size_t)BB * TT * TT;
    float* deg  = ws + off; off += (size_t)BB * NN;
    float* dmax = ws + off; off += 8;
    short* xn16 = (short*)(ws + off); off += (size_t)BB * TT * DD / 2;
    short* qb16 = (short*)(ws + off); off += (size_t)BB * TT * DD / 2;
    short* kb16 = (short*)(ws + off); off += (size_t)BB * TT * DD / 2;
    short* vb16 = (short*)(ws + off); off += (size_t)BB * TT * DD / 2;
    short* vtb  = (short*)(ws + off); off += (size_t)BB * HH * DKK * TP / 2;
    short* ab16 = (short*)(ws + off); off += (size_t)BB * TT * DD / 2;
    short* hb16 = (short*)(ws + off); off += (size_t)BB * TT * DD / 2;
    short* wt   = (short*)(ws + off); off += (size_t)36 * DD * DD / 2;

    const int M = BB * TT;   // 6152

    deg_kernel<<<(BB * NN) / 4, 256, 0, stream>>>(adj, deg);
    degmax_kernel<<<BB, 256, 0, stream>>>(deg, dmax);

    long long total = (long long)BB * TT * TT;
    bias_kernel<<<(int)((total + 255) / 256), 256, 0, stream>>>(
        dist, eoh, adj, deg, dmax, etw, noedge, degsc, gamma, v2n, n2v, vself, bias);

    nodeproj_kernel<<<M, 256, 0, stream>>>(node_feats, npw, npb, cls, x);

    dim3 gw(4, 4, 36);
    wtrans_kernel<<<gw, 256, 0, stream>>>(qw, kw, vw, ow, f1w, f2w, wt);

    dim3 gg((M + 63) / 64, 4);          // (97,4)
    dim3 ga(13, HH, BB);
    dim3 gvt(26, HH, BB);
    const size_t WSZ = (size_t)DD * DD; // 65536
    for (int l = 0; l < LL; ++l) {
        size_t bo = (size_t)l * DD;
        ln_kernel<<<M, 256, 0, stream>>>(x, ln1g + bo, ln1b + bo, xn16);
        gemm_mfma_kernel<<<gg, 256, 0, stream>>>(xn16, wt + (0 * 6 + l) * WSZ, qb + bo, nullptr, qb16, M, 0);
        gemm_mfma_kernel<<<gg, 256, 0, stream>>>(xn16, wt + (1 * 6 + l) * WSZ, kb + bo, nullptr, kb16, M, 0);
        gemm_mfma_kernel<<<gg, 256, 0, stream>>>(xn16, wt + (2 * 6 + l) * WSZ, vb + bo, nullptr, vb16, M, 0);
        vtrans_kernel<<<gvt, 256, 0, stream>>>(vb16, vtb);
        attn_mfma_kernel<<<ga, 256, 0, stream>>>(qb16, kb16, vtb, bias, ab16);
        gemm_mfma_kernel<<<gg, 256, 0, stream>>>(ab16, wt + (3 * 6 + l) * WSZ, ob + bo, x, x, M, 1);
        ln_kernel<<<M, 256, 0, stream>>>(x, ln2g + bo, ln2b + bo, xn16);
        gemm_mfma_kernel<<<gg, 256, 0, stream>>>(xn16, wt + (4 * 6 + l) * WSZ, f1b + bo, nullptr, hb16, M, 2);
        gemm_mfma_kernel<<<gg, 256, 0, stream>>>(hb16, wt + (5 * 6 + l) * WSZ, f2b + bo, x, x, M, 1);
    }
}

// Round 4
// 1087.501 us; speedup vs baseline: 2.5151x; 1.0033x over previous
//
#include <hip/hip_runtime.h>
#include <math.h>

#define BB 8
#define NN 768
#define TT 769
#define PP 772               // bias row pitch (f32), rows 16B-aligned
#define DD 256
#define HH 8
#define DKK 32
#define FF 128
#define LL 6
#define SCALE 0.17677669529663687f   // 1/sqrt(32)
#define TP 832               // vt row pitch (keys padded)
#define NCH 13               // 13 x 64-key chunks
#define BPW 776              // bias LDS pitch (shorts)

typedef __attribute__((ext_vector_type(8))) short s16x8;
typedef __attribute__((ext_vector_type(4))) float f32x4;

__device__ inline short f2bf(float x) {
    unsigned u = __float_as_uint(x);
    unsigned r = (u + 0x7FFFu + ((u >> 16) & 1u)) >> 16;   // RNE
    return (short)r;
}
__device__ inline float bf2f(unsigned short s) {
    return __uint_as_float(((unsigned)s) << 16);
}
__device__ inline float gelu_f(float x) {
    return 0.5f * x * (1.f + erff(x * 0.70710678118654752f));
}

// ---------------- degree ----------------
__global__ __launch_bounds__(256) void deg_kernel(const int* __restrict__ adj,
                                                  float* __restrict__ deg) {
    int row  = blockIdx.x * 4 + (threadIdx.x >> 6);
    int lane = threadIdx.x & 63;
    const int* p = adj + (size_t)row * NN;
    int s = 0;
#pragma unroll
    for (int i = 0; i < NN / 64; ++i) s += p[lane + 64 * i];
#pragma unroll
    for (int off = 32; off > 0; off >>= 1) s += __shfl_xor(s, off);
    if (lane == 0) deg[row] = (float)s;
}

__global__ __launch_bounds__(256) void degmax_kernel(const float* __restrict__ deg,
                                                     float* __restrict__ dmax) {
    __shared__ float red[256];
    int b = blockIdx.x, t = threadIdx.x;
    float m = 0.f;
    for (int i = t; i < NN; i += 256) m = fmaxf(m, deg[b * NN + i]);
    red[t] = m;
    __syncthreads();
    for (int s = 128; s > 0; s >>= 1) {
        if (t < s) red[t] = fmaxf(red[t], red[t + s]);
        __syncthreads();
    }
    if (t == 0) dmax[b] = red[0];
}

// ---------------- attention bias (B,TT,PP) f32, pitch-772 ----------------
__global__ __launch_bounds__(256) void bias_kernel(
    const float* __restrict__ dist, const float* __restrict__ eoh,
    const int* __restrict__ adj, const float* __restrict__ deg,
    const float* __restrict__ dmax, const float* __restrict__ etw,
    const float* __restrict__ noedge, const float* __restrict__ degsc,
    const float* __restrict__ gamma, const float* __restrict__ v2n,
    const float* __restrict__ n2v, const float* __restrict__ vself,
    float* __restrict__ bias)
{
    long long idx = (long long)blockIdx.x * 256 + threadIdx.x;
    const long long total = (long long)BB * TT * PP;
    if (idx >= total) return;
    int b  = (int)(idx / ((long long)TT * PP));
    int r  = (int)(idx % ((long long)TT * PP));
    int qi = r / PP, kj = r % PP;
    float out;
    if (kj >= TT)             out = 0.f;
    else if (qi == 0 && kj == 0) out = vself[0];
    else if (qi == 0)         out = v2n[0];
    else if (kj == 0)         out = n2v[0];
    else {
        int i = qi - 1, j = kj - 1;
        size_t e = ((size_t)b * NN + i) * NN + j;
        float4 oh = *(const float4*)(eoh + 4 * e);
        float val = oh.x * etw[0] + oh.y * etw[1] + oh.z * etw[2] + oh.w * etw[3]
                    - gamma[0] * dist[e];
        if (adj[e] == 0) val += noedge[0];
        val += degsc[0] * (deg[b * NN + i] + deg[b * NN + j]) / (dmax[b] + 1e-6f);
        out = val;
    }
    bias[idx] = out;
}

// ---------------- node projection + cls (writes f32 x in d_out) ----------------
__global__ __launch_bounds__(256) void nodeproj_kernel(
    const float* __restrict__ nf, const float* __restrict__ w,
    const float* __restrict__ bsv, const float* __restrict__ cls,
    float* __restrict__ x)
{
    int row = blockIdx.x;
    int t = threadIdx.x;
    int b = row / TT, tr = row % TT;
    if (tr == 0) { x[(size_t)row * DD + t] = cls[t]; return; }
    __shared__ float sf[FF];
    int i = tr - 1;
    if (t < FF) sf[t] = nf[((size_t)b * NN + i) * FF + t];
    __syncthreads();
    float acc = bsv[t];
#pragma unroll 8
    for (int k = 0; k < FF; ++k) acc = fmaf(sf[k], w[k * DD + t], acc);
    x[(size_t)row * DD + t] = acc;
}

// ---------------- layernorm, wave-per-row (no barriers) -> bf16 ----------------
__global__ __launch_bounds__(256) void ln_kernel(
    const float* __restrict__ x, const float* __restrict__ g,
    const float* __restrict__ bsv, short* __restrict__ out)
{
    int t = threadIdx.x, wid = t >> 6, lane = t & 63;
    int row = blockIdx.x * 4 + wid;
    float4 v = *(const float4*)(x + (size_t)row * DD + lane * 4);
    float s = v.x + v.y + v.z + v.w;
#pragma unroll
    for (int off = 32; off > 0; off >>= 1) s += __shfl_xor(s, off);
    float mean = s * (1.f / DD);
    float dx = v.x - mean, dy = v.y - mean, dz = v.z - mean, dw = v.w - mean;
    float q = dx * dx + dy * dy + dz * dz + dw * dw;
#pragma unroll
    for (int off = 32; off > 0; off >>= 1) q += __shfl_xor(q, off);
    float inv = rsqrtf(q * (1.f / DD) + 1e-5f);
    float4 gv = *(const float4*)(g + lane * 4);
    float4 bv = *(const float4*)(bsv + lane * 4);
    short4 o4;
    o4.x = f2bf(dx * inv * gv.x + bv.x);
    o4.y = f2bf(dy * inv * gv.y + bv.y);
    o4.z = f2bf(dz * inv * gv.z + bv.z);
    o4.w = f2bf(dw * inv * gv.w + bv.w);
    *(short4*)(out + (size_t)row * DD + lane * 4) = o4;
}

// ---------------- weight transpose+cast: 36 x (256,256) f32 -> bf16 W^T ----------------
__global__ __launch_bounds__(256) void wtrans_kernel(
    const float* __restrict__ qw, const float* __restrict__ kw,
    const float* __restrict__ vw, const float* __restrict__ ow,
    const float* __restrict__ f1w, const float* __restrict__ f2w,
    short* __restrict__ wt)
{
    __shared__ short tile[64][72];
    int mi = blockIdx.z;              // family*6 + layer
    int fam = mi / 6, l = mi % 6;
    const float* W;
    if      (fam == 0) W = qw;
    else if (fam == 1) W = kw;
    else if (fam == 2) W = vw;
    else if (fam == 3) W = ow;
    else if (fam == 4) W = f1w;
    else               W = f2w;
    W += (size_t)l * DD * DD;
    int k0 = blockIdx.x * 64, n0 = blockIdx.y * 64;
    int t = threadIdx.x;
    int r = t >> 2, cs = (t & 3) * 16;
#pragma unroll
    for (int i = 0; i < 4; ++i) {
        float4 v4 = *(const float4*)(W + (size_t)(k0 + r) * DD + n0 + cs + i * 4);
        tile[r][cs + i * 4 + 0] = f2bf(v4.x);
        tile[r][cs + i * 4 + 1] = f2bf(v4.y);
        tile[r][cs + i * 4 + 2] = f2bf(v4.z);
        tile[r][cs + i * 4 + 3] = f2bf(v4.w);
    }
    __syncthreads();
    int nl = t >> 2, ks = (t & 3) * 16;
    short* op = wt + (size_t)mi * DD * DD + (size_t)(n0 + nl) * DD + k0 + ks;
#pragma unroll
    for (int j = 0; j < 16; ++j) op[j] = tile[ks + j][nl];
}

// ---------------- LDS-free barrier-free bf16 GEMM, N=256 families ----------------
// block 256 = 4 waves, block tile 64 rows x 64 cols; wave = 16 rows x 64 cols.
// omode: 1 = f32 out + resid, 2 = gelu bf16 out
__global__ __launch_bounds__(256, 4) void gemm_kernel(
    const short* __restrict__ A, const short* __restrict__ Wt,
    const float* __restrict__ bsv, const float* __restrict__ resid,
    void* __restrict__ out, int M, int omode)
{
    int t = threadIdx.x;
    int wv = t >> 6, lane = t & 63, quad = lane >> 4, m16 = lane & 15;
    int m0 = blockIdx.x * 64, n0 = blockIdx.y * 64;
    int rowbase = m0 + wv * 16;
    int arow = rowbase + m16; if (arow >= M) arow = M - 1;
    const short* ap = A + (size_t)arow * DD + quad * 8;
    const short* bp = Wt + (size_t)(n0 + m16) * DD + quad * 8;
    f32x4 acc[4] = {};
#pragma unroll
    for (int k0 = 0; k0 < DD; k0 += 32) {
        s16x8 af = *(const s16x8*)(ap + k0);
#pragma unroll
        for (int c = 0; c < 4; ++c) {
            s16x8 bf = *(const s16x8*)(bp + (size_t)c * 16 * DD + k0);
            acc[c] = __builtin_amdgcn_mfma_f32_16x16x32_bf16(af, bf, acc[c], 0, 0, 0);
        }
    }
#pragma unroll
    for (int c = 0; c < 4; ++c) {
        int col = n0 + c * 16 + m16;
        float bv = bsv[col];
#pragma unroll
        for (int r = 0; r < 4; ++r) {
            int row = rowbase + quad * 4 + r;
            if (row >= M) continue;
            float v = acc[c][r] + bv;
            size_t idx = (size_t)row * DD + col;
            if (omode == 2) ((short*)out)[idx] = f2bf(gelu_f(v));
            else            ((float*)out)[idx] = v + resid[idx];
        }
    }
}

// ---------------- fused QKV GEMM: N=768 (3 families), bf16 out ----------------
__global__ __launch_bounds__(256, 4) void gemm_qkv_kernel(
    const short* __restrict__ A, const short* __restrict__ wtl,
    const float* __restrict__ qb, const float* __restrict__ kb,
    const float* __restrict__ vb,
    short* __restrict__ qo, short* __restrict__ ko, short* __restrict__ vo,
    int M)
{
    int t = threadIdx.x;
    int wv = t >> 6, lane = t & 63, quad = lane >> 4, m16 = lane & 15;
    int fam = blockIdx.y >> 2;
    int n0 = (blockIdx.y & 3) * 64;
    const short* Wt = wtl + (size_t)fam * 6 * DD * DD;
    const float* bsv = fam == 0 ? qb : (fam == 1 ? kb : vb);
    short* out = fam == 0 ? qo : (fam == 1 ? ko : vo);
    int m0 = blockIdx.x * 64;
    int rowbase = m0 + wv * 16;
    int arow = rowbase + m16; if (arow >= M) arow = M - 1;
    const short* ap = A + (size_t)arow * DD + quad * 8;
    const short* bp = Wt + (size_t)(n0 + m16) * DD + quad * 8;
    f32x4 acc[4] = {};
#pragma unroll
    for (int k0 = 0; k0 < DD; k0 += 32) {
        s16x8 af = *(const s16x8*)(ap + k0);
#pragma unroll
        for (int c = 0; c < 4; ++c) {
            s16x8 bf = *(const s16x8*)(bp + (size_t)c * 16 * DD + k0);
            acc[c] = __builtin_amdgcn_mfma_f32_16x16x32_bf16(af, bf, acc[c], 0, 0, 0);
        }
    }
#pragma unroll
    for (int c = 0; c < 4; ++c) {
        int col = n0 + c * 16 + m16;
        float bv = bsv[col];
#pragma unroll
        for (int r = 0; r < 4; ++r) {
            int row = rowbase + quad * 4 + r;
            if (row >= M) continue;
            out[(size_t)row * DD + col] = f2bf(acc[c][r] + bv);
        }
    }
}

// ---------------- V transpose: vb16 (B,T,256) -> vt (B,H,32,TP) ----------------
__global__ __launch_bounds__(256) void vtrans_kernel(const short* __restrict__ v,
                                                     short* __restrict__ vt)
{
    __shared__ short tile[32][33];
    int b = blockIdx.z, h = blockIdx.y, t0 = blockIdx.x * 32;
    int dk = threadIdx.x & 31, tr = threadIdx.x >> 5;
#pragma unroll
    for (int i = 0; i < 4; ++i) {
        int tl = tr + i * 8;
        int tt = t0 + tl;
        short val = 0;
        if (tt < TT) val = v[((size_t)(b * TT + tt)) * DD + h * DKK + dk];
        tile[tl][dk] = val;
    }
    __syncthreads();
    int tl = threadIdx.x & 31, dko = threadIdx.x >> 5;
#pragma unroll
    for (int i = 0; i < 4; ++i) {
        int d = dko + i * 8;
        vt[(((size_t)(b * HH + h)) * DKK + d) * TP + t0 + tl] = tile[tl][d];
    }
}

// ---------------- flash attention: 8 heads/block, bias LDS-resident ----------------
// grid (49, 8): x = 16-row q-tile, y = batch. block 512 = 8 waves = 8 heads.
__global__ __launch_bounds__(512, 4) void attn_mfma_kernel(
    const short* __restrict__ q, const short* __restrict__ k,
    const short* __restrict__ vt, const float* __restrict__ bias,
    short* __restrict__ o)
{
    __shared__ unsigned short bs[16 * BPW + 64];   // bf16 bias tile + slack
    __shared__ short Pb[8][16][72];                // per-wave P buffer
    int t = threadIdx.x;
    int wid = t >> 6, lane = t & 63;
    int quad = lane >> 4, m16 = lane & 15;
    int b = blockIdx.y, h = wid;
    int q0 = blockIdx.x * 16;

    // ---- stage bias tile (16 rows x 772 cols) -> bf16 LDS, once ----
    for (int i = t; i < 16 * 193; i += 512) {
        int row = i / 193, c4 = (i - row * 193) * 4;
        int qr = q0 + row; if (qr >= TT) qr = TT - 1;
        float4 v = *(const float4*)(bias + ((size_t)(b * TT + qr)) * PP + c4);
        unsigned short* dst = &bs[row * BPW + c4];
        dst[0] = (unsigned short)f2bf(v.x);
        dst[1] = (unsigned short)f2bf(v.y);
        dst[2] = (unsigned short)f2bf(v.z);
        dst[3] = (unsigned short)f2bf(v.w);
    }

    int qrow = q0 + m16;
    int qc = qrow < TT ? qrow : TT - 1;
    s16x8 qa = *(const s16x8*)(q + ((size_t)(b * TT + qc)) * DD + h * DKK + quad * 8);

    f32x4 oacc0 = {0.f, 0.f, 0.f, 0.f};
    f32x4 oacc1 = {0.f, 0.f, 0.f, 0.f};
    float mrow[4], lsum[4];
#pragma unroll
    for (int r = 0; r < 4; ++r) { mrow[r] = -1e30f; lsum[r] = 0.f; }

    const short* kbase = k + ((size_t)(b * TT)) * DD + h * DKK + quad * 8;
    const short* vbase = vt + (((size_t)(b * HH + h)) * DKK) * TP;

    // prefetch chunk-0 K frags
    s16x8 kc[4], kn[4];
#pragma unroll
    for (int s = 0; s < 4; ++s) {
        int kr = s * 16 + m16;
        int kcl = kr < TT ? kr : TT - 1;
        kc[s] = *(const s16x8*)(kbase + (size_t)kcl * DD);
    }
    __syncthreads();   // bias tile visible

    for (int c = 0; c < NCH; ++c) {
        int j0 = c * 64;
        if (c + 1 < NCH) {
            int jn = j0 + 64;
#pragma unroll
            for (int s = 0; s < 4; ++s) {
                int kr = jn + s * 16 + m16;
                int kcl = kr < TT ? kr : TT - 1;
                kn[s] = *(const s16x8*)(kbase + (size_t)kcl * DD);
            }
        }
        f32x4 z = {0.f, 0.f, 0.f, 0.f};
        f32x4 sacc[4];
#pragma unroll
        for (int s = 0; s < 4; ++s)
            sacc[s] = __builtin_amdgcn_mfma_f32_16x16x32_bf16(qa, kc[s], z, 0, 0, 0);

        float sv[16];
#pragma unroll
        for (int s = 0; s < 4; ++s) {
            int key = j0 + s * 16 + m16;
            int kvld = key < TT;
#pragma unroll
            for (int r = 0; r < 4; ++r) {
                float bv = bf2f(bs[(quad * 4 + r) * BPW + key]);
                sv[s * 4 + r] = kvld ? sacc[s][r] * SCALE + bv : -1e30f;
            }
        }

#pragma unroll
        for (int r = 0; r < 4; ++r) {
            float mx = fmaxf(fmaxf(sv[r], sv[4 + r]), fmaxf(sv[8 + r], sv[12 + r]));
#pragma unroll
            for (int off = 1; off < 16; off <<= 1) mx = fmaxf(mx, __shfl_xor(mx, off));
            float mnew = fmaxf(mrow[r], mx);
            float alpha = __expf(mrow[r] - mnew);
            mrow[r] = mnew;
            float ps = 0.f;
#pragma unroll
            for (int s = 0; s < 4; ++s) {
                float p = __expf(sv[s * 4 + r] - mnew);
                sv[s * 4 + r] = p;
                ps += p;
            }
            lsum[r] = lsum[r] * alpha + ps;
            oacc0[r] *= alpha; oacc1[r] *= alpha;
        }

        // P: C-layout -> A-layout via wave-private LDS
#pragma unroll
        for (int s = 0; s < 4; ++s)
#pragma unroll
            for (int r = 0; r < 4; ++r)
                Pb[wid][quad * 4 + r][s * 16 + m16] = f2bf(sv[s * 4 + r]);
        s16x8 pa0 = *(const s16x8*)(&Pb[wid][m16][quad * 8]);
        s16x8 pa1 = *(const s16x8*)(&Pb[wid][m16][32 + quad * 8]);

        s16x8 va;
        va = *(const s16x8*)(vbase + (size_t)m16 * TP + j0 + quad * 8);
        oacc0 = __builtin_amdgcn_mfma_f32_16x16x32_bf16(pa0, va, oacc0, 0, 0, 0);
        va = *(const s16x8*)(vbase + (size_t)m16 * TP + j0 + 32 + quad * 8);
        oacc0 = __builtin_amdgcn_mfma_f32_16x16x32_bf16(pa1, va, oacc0, 0, 0, 0);
        va = *(const s16x8*)(vbase + (size_t)(16 + m16) * TP + j0 + quad * 8);
        oacc1 = __builtin_amdgcn_mfma_f32_16x16x32_bf16(pa0, va, oacc1, 0, 0, 0);
        va = *(const s16x8*)(vbase + (size_t)(16 + m16) * TP + j0 + 32 + quad * 8);
        oacc1 = __builtin_amdgcn_mfma_f32_16x16x32_bf16(pa1, va, oacc1, 0, 0, 0);

#pragma unroll
        for (int s = 0; s < 4; ++s) kc[s] = kn[s];
    }

#pragma unroll
    for (int r = 0; r < 4; ++r) {
#pragma unroll
        for (int off = 1; off < 16; off <<= 1) lsum[r] += __shfl_xor(lsum[r], off);
        int qr = q0 + quad * 4 + r;
        if (qr < TT) {
            float inv = 1.f / lsum[r];
            short* op = o + ((size_t)(b * TT + qr)) * DD + h * DKK;
            op[m16]      = f2bf(oacc0[r] * inv);
            op[16 + m16] = f2bf(oacc1[r] * inv);
        }
    }
}

// ---------------- host ----------------
extern "C" void kernel_launch(void* const* d_in, const int* in_sizes, int n_in,
                              void* d_out, int out_size, void* d_ws, size_t ws_size,
                              hipStream_t stream)
{
    const float* node_feats = (const float*)d_in[0];
    const int*   adj        = (const int*)d_in[1];
    const float* dist       = (const float*)d_in[2];
    const float* eoh        = (const float*)d_in[3];
    const float* npw        = (const float*)d_in[4];
    const float* npb        = (const float*)d_in[5];
    const float* cls        = (const float*)d_in[6];
    const float* etw        = (const float*)d_in[7];
    const float* noedge     = (const float*)d_in[8];
    const float* degsc      = (const float*)d_in[9];
    const float* gamma      = (const float*)d_in[10];
    const float* v2n        = (const float*)d_in[11];
    const float* n2v        = (const float*)d_in[12];
    const float* vself      = (const float*)d_in[13];
    const float* ln1g = (const float*)d_in[14];
    const float* ln1b = (const float*)d_in[15];
    const float* qw   = (const float*)d_in[16];
    const float* qb   = (const float*)d_in[17];
    const float* kw   = (const float*)d_in[18];
    const float* kb   = (const float*)d_in[19];
    const float* vw   = (const float*)d_in[20];
    const float* vb   = (const float*)d_in[21];
    const float* ow   = (const float*)d_in[22];
    const float* ob   = (const float*)d_in[23];
    const float* ln2g = (const float*)d_in[24];
    const float* ln2b = (const float*)d_in[25];
    const float* f1w  = (const float*)d_in[26];
    const float* f1b  = (const float*)d_in[27];
    const float* f2w  = (const float*)d_in[28];
    const float* f2b  = (const float*)d_in[29];

    float* x  = (float*)d_out;   // (B,T,D) f32 residual stream
    float* ws = (float*)d_ws;
    size_t off = 0;
    float* bias = ws + off; off += (size_t)BB * TT * PP;    // pitch-772
    float* deg  = ws + off; off += (size_t)BB * NN;
    float* dmax = ws + off; off += 8;
    short* xn16 = (short*)(ws + off); off += (size_t)BB * TT * DD / 2;
    short* qb16 = (short*)(ws + off); off += (size_t)BB * TT * DD / 2;
    short* kb16 = (short*)(ws + off); off += (size_t)BB * TT * DD / 2;
    short* vb16 = (short*)(ws + off); off += (size_t)BB * TT * DD / 2;
    short* vtb  = (short*)(ws + off); off += (size_t)BB * HH * DKK * TP / 2;
    short* ab16 = (short*)(ws + off); off += (size_t)BB * TT * DD / 2;
    short* hb16 = (short*)(ws + off); off += (size_t)BB * TT * DD / 2;
    short* wt   = (short*)(ws + off); off += (size_t)36 * DD * DD / 2;

    const int M = BB * TT;   // 6152

    deg_kernel<<<(BB * NN) / 4, 256, 0, stream>>>(adj, deg);
    degmax_kernel<<<BB, 256, 0, stream>>>(deg, dmax);

    long long total = (long long)BB * TT * PP;
    bias_kernel<<<(int)((total + 255) / 256), 256, 0, stream>>>(
        dist, eoh, adj, deg, dmax, etw, noedge, degsc, gamma, v2n, n2v, vself, bias);

    nodeproj_kernel<<<M, 256, 0, stream>>>(node_feats, npw, npb, cls, x);

    dim3 gw(4, 4, 36);
    wtrans_kernel<<<gw, 256, 0, stream>>>(qw, kw, vw, ow, f1w, f2w, wt);

    dim3 gqkv((M + 63) / 64, 12);       // (97,12)
    dim3 gg((M + 63) / 64, 4);          // (97,4)
    dim3 ga(49, BB);
    dim3 gvt(26, HH, BB);
    const size_t WSZ = (size_t)DD * DD; // 65536
    for (int l = 0; l < LL; ++l) {
        size_t bo = (size_t)l * DD;
        ln_kernel<<<M / 4, 256, 0, stream>>>(x, ln1g + bo, ln1b + bo, xn16);
        gemm_qkv_kernel<<<gqkv, 256, 0, stream>>>(xn16, wt + l * WSZ,
                                                  qb + bo, kb + bo, vb + bo,
                                                  qb16, kb16, vb16, M);
        vtrans_kernel<<<gvt, 256, 0, stream>>>(vb16, vtb);
        attn_mfma_kernel<<<ga, 512, 0, stream>>>(qb16, kb16, vtb, bias, ab16);
        gemm_kernel<<<gg, 256, 0, stream>>>(ab16, wt + (3 * 6 + l) * WSZ, ob + bo, x, x, M, 1);
        ln_kernel<<<M / 4, 256, 0, stream>>>(x, ln2g + bo, ln2b + bo, xn16);
        gemm_kernel<<<gg, 256, 0, stream>>>(xn16, wt + (4 * 6 + l) * WSZ, f1b + bo, nullptr, hb16, M, 2);
        gemm_kernel<<<gg, 256, 0, stream>>>(hb16, wt + (5 * 6 + l) * WSZ, f2b + bo, x, x, M, 1);
    }
}